// Round 1
// baseline (1862.620 us; speedup 1.0000x reference)
//
#include <hip/hip_runtime.h>

typedef float  float4v  __attribute__((ext_vector_type(4)));
typedef int    int4v    __attribute__((ext_vector_type(4)));
typedef unsigned short ushort4v __attribute__((ext_vector_type(4)));
typedef __bf16 bf16x8   __attribute__((ext_vector_type(8)));

#define D_MODEL 1024
#define NHEAD   16
#define HEAD_DIM 64
#define D_FF    4096
#define SEQ     2048
#define NBATCH  4
#define NTOK    (SEQ*NBATCH)   // 8192

__device__ __forceinline__ unsigned short f2bf(float f){
  unsigned int u = __builtin_bit_cast(unsigned int, f);
  u += 0x7FFFu + ((u >> 16) & 1u);          // round-to-nearest-even
  return (unsigned short)(u >> 16);
}
__device__ __forceinline__ float bf2f(unsigned short h){
  unsigned int u = ((unsigned int)h) << 16;
  return __builtin_bit_cast(float, u);
}

// ---------------------------------------------------------------------------
// Transpose + fp32->bf16: in [K,N] row-major -> out [N,K] row-major (K-contig)
// ---------------------------------------------------------------------------
__global__ __launch_bounds__(256)
void transpose_bf16_k(const float* __restrict__ in, unsigned short* __restrict__ out,
                      int K, int N)
{
  __shared__ float t[32][33];
  const int n0 = blockIdx.x * 32, k0 = blockIdx.y * 32;
  const int tx = threadIdx.x & 31, ty = threadIdx.x >> 5;   // 32 x 8
  #pragma unroll
  for(int i=0;i<32;i+=8) t[ty+i][tx] = in[(long)(k0+ty+i)*N + n0 + tx];
  __syncthreads();
  #pragma unroll
  for(int i=0;i<32;i+=8) out[(long)(n0+ty+i)*K + k0 + tx] = f2bf(t[tx][ty+i]);
}

// ---------------------------------------------------------------------------
// LayerNorm over 1024 cols, fp32 in -> bf16 out. One 256-thread block per row.
// ---------------------------------------------------------------------------
__global__ __launch_bounds__(256)
void ln_bf16(const float* __restrict__ x, const float* __restrict__ g,
             const float* __restrict__ b, unsigned short* __restrict__ out)
{
  const int row = blockIdx.x, tid = threadIdx.x;
  const float* xr = x + (long)row * D_MODEL;
  float4v v = *(const float4v*)(xr + tid*4);
  float s = v[0]+v[1]+v[2]+v[3];
  float q = v[0]*v[0]+v[1]*v[1]+v[2]*v[2]+v[3]*v[3];
  #pragma unroll
  for(int off=32; off; off>>=1){ s += __shfl_down(s, off); q += __shfl_down(q, off); }
  __shared__ float sb[4], qb[4], stat[2];
  const int w = tid>>6, lane = tid&63;
  if(lane==0){ sb[w]=s; qb[w]=q; }
  __syncthreads();
  if(tid==0){
    float S = sb[0]+sb[1]+sb[2]+sb[3];
    float Q = qb[0]+qb[1]+qb[2]+qb[3];
    float mean = S * (1.0f/D_MODEL);
    float var  = Q * (1.0f/D_MODEL) - mean*mean;
    stat[0] = mean;
    stat[1] = rsqrtf(var + 1e-5f);
  }
  __syncthreads();
  const float mean = stat[0], rstd = stat[1];
  ushort4v o;
  #pragma unroll
  for(int i=0;i<4;i++){
    int c = tid*4 + i;
    o[i] = f2bf((v[i]-mean)*rstd*g[c] + b[c]);
  }
  *(ushort4v*)(out + (long)row*D_MODEL + tid*4) = o;
}

// ---------------------------------------------------------------------------
// bf16 MFMA GEMM: C[M,N] = A[M,K] @ B[K,N] (+bias, epilogue variants)
// A: [M,K] bf16 (K-contig). Bt: [N,K] bf16 (K-contig, i.e. B transposed).
// 128x128 block tile, 256 thr = 4 waves (2x2), each wave 64x64 = 4x4 MFMA
// tiles of 16x16x32. EPI: 0 bias->bf16 out; 1 bias+relu->bf16; 2 bias+res->f32.
// ---------------------------------------------------------------------------
template<int EPI>
__global__ __launch_bounds__(256, 2)
void gemm_bf16(const unsigned short* __restrict__ A,
               const unsigned short* __restrict__ Bt,
               const float* __restrict__ bias,
               const float* __restrict__ res,
               void* __restrict__ Cout,
               int M, int N, int K)
{
  __shared__ unsigned short As[128][40];   // pad +8 bf16, keeps 16B align
  __shared__ unsigned short Bs[128][40];
  const int tid = threadIdx.x;
  const int bm = blockIdx.x, bn = blockIdx.y;
  const int lane = tid & 63, wave = tid >> 6;
  const int wm = (wave >> 1) * 64, wn = (wave & 1) * 64;
  const int lrow = lane & 15, lquad = lane >> 4;

  float4v acc[4][4];
  #pragma unroll
  for(int i=0;i<4;i++)
    #pragma unroll
    for(int j=0;j<4;j++){ float4v z = {0.f,0.f,0.f,0.f}; acc[i][j] = z; }

  const long ra0 = (long)bm * 128;
  const long rb0 = (long)bn * 128;

  for(int k0 = 0; k0 < K; k0 += 32){
    __syncthreads();
    // stage 128x32 bf16 tiles: 512 chunks of 8 bf16, 2 chunks/thread
    #pragma unroll
    for(int c=0;c<2;c++){
      int ch = c*256 + tid;
      int r = ch >> 2, pos = (ch & 3) * 8;
      *(int4v*)&As[r][pos] = *(const int4v*)(A  + (ra0 + r)*K + k0 + pos);
      *(int4v*)&Bs[r][pos] = *(const int4v*)(Bt + (rb0 + r)*K + k0 + pos);
    }
    __syncthreads();
    bf16x8 af[4], bfr[4];
    #pragma unroll
    for(int i=0;i<4;i++){
      af[i]  = *(const bf16x8*)&As[wm + i*16 + lrow][lquad*8];
      bfr[i] = *(const bf16x8*)&Bs[wn + i*16 + lrow][lquad*8];
    }
    #pragma unroll
    for(int i=0;i<4;i++)
      #pragma unroll
      for(int j=0;j<4;j++)
        acc[i][j] = __builtin_amdgcn_mfma_f32_16x16x32_bf16(af[i], bfr[j], acc[i][j], 0, 0, 0);
  }

  #pragma unroll
  for(int i=0;i<4;i++){
    #pragma unroll
    for(int r=0;r<4;r++){
      const int row = bm*128 + wm + i*16 + lquad*4 + r;
      const long base = (long)row * N + bn*128 + wn;
      #pragma unroll
      for(int j=0;j<4;j++){
        const int ct = j*16 + lrow;
        float val = acc[i][j][r] + bias[bn*128 + wn + ct];
        if constexpr (EPI == 1) val = fmaxf(val, 0.f);
        if constexpr (EPI == 2)
          ((float*)Cout)[base + ct] = val + res[base + ct];
        else
          ((unsigned short*)Cout)[base + ct] = f2bf(val);
      }
    }
  }
}

// ---------------------------------------------------------------------------
// Flash-style attention, fp32 vector math. 1 thread = 1 q row, online softmax.
// q/k/v: [NTOK, D_MODEL] bf16, head h at column offset h*64.
// grid = (SEQ/256, NHEAD, NBATCH)
// ---------------------------------------------------------------------------
__global__ __launch_bounds__(256, 2)
void attn_vec(const unsigned short* __restrict__ qm,
              const unsigned short* __restrict__ km,
              const unsigned short* __restrict__ vm,
              unsigned short* __restrict__ om)
{
  __shared__ float Ks[128][64];
  __shared__ float Vs[128][64];
  const int tid = threadIdx.x;
  const int qc = blockIdx.x, h = blockIdx.y, n = blockIdx.z;
  const int qrow = qc*256 + tid;
  const long qg = ((long)(n*SEQ + qrow))*D_MODEL + h*HEAD_DIM;

  float qr[64];
  #pragma unroll
  for(int d=0; d<64; d++) qr[d] = bf2f(qm[qg + d]) * 0.125f;  // scale = 1/sqrt(64)

  float m = -1e30f, l = 0.f;
  float o_acc[64];
  #pragma unroll
  for(int d=0; d<64; d++) o_acc[d] = 0.f;

  const long kb = ((long)n*SEQ)*D_MODEL + h*HEAD_DIM;
  for(int s0=0; s0<SEQ; s0+=128){
    __syncthreads();
    for(int e=tid; e<128*64; e+=256){
      int r = e>>6, d = e&63;
      long ga = kb + (long)(s0 + r)*D_MODEL + d;
      Ks[r][d] = bf2f(km[ga]);
      Vs[r][d] = bf2f(vm[ga]);
    }
    __syncthreads();
    for(int ss=0; ss<128; ss++){
      const float4v* kr = (const float4v*)&Ks[ss][0];
      float a0=0.f,a1=0.f,a2=0.f,a3=0.f;
      #pragma unroll
      for(int d4=0; d4<16; d4++){
        float4v kk = kr[d4];
        a0 += qr[d4*4+0]*kk[0];
        a1 += qr[d4*4+1]*kk[1];
        a2 += qr[d4*4+2]*kk[2];
        a3 += qr[d4*4+3]*kk[3];
      }
      float sc = (a0+a1)+(a2+a3);
      if(sc > m){                 // rare after warm-up (~log(S) times per row)
        float corr = __expf(m - sc);
        l *= corr;
        #pragma unroll
        for(int d=0; d<64; d++) o_acc[d] *= corr;
        m = sc;
      }
      float p = __expf(sc - m);
      l += p;
      const float4v* vr = (const float4v*)&Vs[ss][0];
      #pragma unroll
      for(int d4=0; d4<16; d4++){
        float4v vv = vr[d4];
        o_acc[d4*4+0] += p*vv[0];
        o_acc[d4*4+1] += p*vv[1];
        o_acc[d4*4+2] += p*vv[2];
        o_acc[d4*4+3] += p*vv[3];
      }
    }
  }
  const float inv = 1.f / l;
  #pragma unroll
  for(int d=0; d<64; d+=4){
    ushort4v o;
    o[0]=f2bf(o_acc[d+0]*inv); o[1]=f2bf(o_acc[d+1]*inv);
    o[2]=f2bf(o_acc[d+2]*inv); o[3]=f2bf(o_acc[d+3]*inv);
    *(ushort4v*)(om + qg + d) = o;
  }
}

// ---------------------------------------------------------------------------
// Classifier head + GAN loss. logits[n] = x[n,0,:] @ wlr + blr.
// out[0]=loss, out[1]=loss_fake. One block, wave w handles batch w.
// ---------------------------------------------------------------------------
__global__ __launch_bounds__(256)
void loss_k(const float* __restrict__ xo, const float* __restrict__ wlr,
            const float* __restrict__ blr, float* __restrict__ out)
{
  const int tid = threadIdx.x, w = tid>>6, lane = tid&63;
  const float* row = xo + (long)w * SEQ * D_MODEL;   // token 0 of batch w
  float s = 0.f;
  for(int c=lane; c<D_MODEL; c+=64) s += row[c]*wlr[c];
  #pragma unroll
  for(int off=32; off; off>>=1) s += __shfl_down(s, off);
  __shared__ float lg[4];
  if(lane==0) lg[w] = s + blr[0];
  __syncthreads();
  if(tid==0){
    auto sp = [](float t){ return fmaxf(t, 0.f) + log1pf(__expf(-fabsf(t))); };
    float loss_real = 0.5f*(sp(-lg[0]) + sp(-lg[1]));
    float loss_fake = 0.5f*(sp( lg[2]) + sp( lg[3]));
    out[0] = 0.5f*(loss_fake + loss_real);
    out[1] = loss_fake;
  }
}

// ---------------------------------------------------------------------------
extern "C" void kernel_launch(void* const* d_in, const int* in_sizes, int n_in,
                              void* d_out, int out_size, void* d_ws, size_t ws_size,
                              hipStream_t stream)
{
  const float* x    = (const float*)d_in[0];
  const float* wq   = (const float*)d_in[1];
  const float* bq   = (const float*)d_in[2];
  const float* wk   = (const float*)d_in[3];
  const float* bk   = (const float*)d_in[4];
  const float* wv   = (const float*)d_in[5];
  const float* bv   = (const float*)d_in[6];
  const float* wo   = (const float*)d_in[7];
  const float* bo   = (const float*)d_in[8];
  const float* ln1g = (const float*)d_in[9];
  const float* ln1b = (const float*)d_in[10];
  const float* ln2g = (const float*)d_in[11];
  const float* ln2b = (const float*)d_in[12];
  const float* w1   = (const float*)d_in[13];
  const float* b1   = (const float*)d_in[14];
  const float* w2   = (const float*)d_in[15];
  const float* b2   = (const float*)d_in[16];
  const float* wlr  = (const float*)d_in[17];
  const float* blr  = (const float*)d_in[18];
  float* xout = (float*)d_out;

  // workspace layout (136 MB total), bf16 unless noted:
  char* ws = (char*)d_ws;
  unsigned short* xn   = (unsigned short*)(ws + (size_t)( 0<<20)); // 16MB (xn, later xn2)
  unsigned short* wq_t = (unsigned short*)(ws + (size_t)(16<<20)); //  2MB
  unsigned short* wk_t = (unsigned short*)(ws + (size_t)(18<<20));
  unsigned short* wv_t = (unsigned short*)(ws + (size_t)(20<<20));
  unsigned short* wo_t = (unsigned short*)(ws + (size_t)(22<<20));
  unsigned short* w1_t = (unsigned short*)(ws + (size_t)(24<<20)); //  8MB
  unsigned short* w2_t = (unsigned short*)(ws + (size_t)(32<<20)); //  8MB
  unsigned short* qb   = (unsigned short*)(ws + (size_t)(40<<20)); // 16MB
  unsigned short* kbuf = (unsigned short*)(ws + (size_t)(56<<20)); // 16MB
  unsigned short* vbuf = (unsigned short*)(ws + (size_t)(72<<20)); // 16MB
  unsigned short* attn = (unsigned short*)(ws + (size_t)(88<<20)); // 16MB
  float*          x1   = (float*)         (ws + (size_t)(104<<20));// 32MB fp32
  unsigned short* hid  = (unsigned short*)(ws + (size_t)(40<<20)); // 64MB, aliases q/k/v/attn (dead by then)

  dim3 blk(256);

  // weights -> bf16, transposed to [N,K]
  transpose_bf16_k<<<dim3(32,32),  blk, 0, stream>>>(wq, wq_t, 1024, 1024);
  transpose_bf16_k<<<dim3(32,32),  blk, 0, stream>>>(wk, wk_t, 1024, 1024);
  transpose_bf16_k<<<dim3(32,32),  blk, 0, stream>>>(wv, wv_t, 1024, 1024);
  transpose_bf16_k<<<dim3(32,32),  blk, 0, stream>>>(wo, wo_t, 1024, 1024);
  transpose_bf16_k<<<dim3(128,32), blk, 0, stream>>>(w1, w1_t, 1024, 4096);
  transpose_bf16_k<<<dim3(32,128), blk, 0, stream>>>(w2, w2_t, 4096, 1024);

  // LN1
  ln_bf16<<<NTOK, blk, 0, stream>>>(x, ln1g, ln1b, xn);

  // QKV projections
  gemm_bf16<0><<<dim3(64,8),  blk, 0, stream>>>(xn, wq_t, bq, nullptr, qb,   NTOK, 1024, 1024);
  gemm_bf16<0><<<dim3(64,8),  blk, 0, stream>>>(xn, wk_t, bk, nullptr, kbuf, NTOK, 1024, 1024);
  gemm_bf16<0><<<dim3(64,8),  blk, 0, stream>>>(xn, wv_t, bv, nullptr, vbuf, NTOK, 1024, 1024);

  // attention
  attn_vec<<<dim3(SEQ/256, NHEAD, NBATCH), blk, 0, stream>>>(qb, kbuf, vbuf, attn);

  // out projection + residual -> x1 (fp32)
  gemm_bf16<2><<<dim3(64,8),  blk, 0, stream>>>(attn, wo_t, bo, x, x1, NTOK, 1024, 1024);

  // LN2 (reuse xn buffer)
  ln_bf16<<<NTOK, blk, 0, stream>>>(x1, ln2g, ln2b, xn);

  // FFN
  gemm_bf16<1><<<dim3(64,32), blk, 0, stream>>>(xn,  w1_t, b1, nullptr, hid, NTOK, D_FF, 1024);
  gemm_bf16<2><<<dim3(64,8),  blk, 0, stream>>>(hid, w2_t, b2, x1, xout,     NTOK, 1024, D_FF);

  // classifier head + losses
  loss_k<<<1, blk, 0, stream>>>(xout, wlr, blr, xout + (size_t)NTOK*D_MODEL);
}

// Round 2
// 674.271 us; speedup vs baseline: 2.7624x; 2.7624x over previous
//
#include <hip/hip_runtime.h>

typedef float  float4v  __attribute__((ext_vector_type(4)));
typedef int    int4v    __attribute__((ext_vector_type(4)));
typedef unsigned short ushort4v __attribute__((ext_vector_type(4)));
typedef __bf16 bf16x8   __attribute__((ext_vector_type(8)));

#define D_MODEL 1024
#define NHEAD   16
#define HEAD_DIM 64
#define D_FF    4096
#define SEQ     2048
#define NBATCH  4
#define NTOK    (SEQ*NBATCH)   // 8192

// softmax scale folded into exp2: 1/sqrt(64) * log2(e)
#define SCL 0.18033688011112042f

__device__ __forceinline__ unsigned short f2bf(float f){
  unsigned int u = __builtin_bit_cast(unsigned int, f);
  u += 0x7FFFu + ((u >> 16) & 1u);          // round-to-nearest-even
  return (unsigned short)(u >> 16);
}
__device__ __forceinline__ float bf2f(unsigned short h){
  unsigned int u = ((unsigned int)h) << 16;
  return __builtin_bit_cast(float, u);
}
__device__ __forceinline__ unsigned int pk2bf(float lo, float hi){
  return (unsigned int)f2bf(lo) | ((unsigned int)f2bf(hi) << 16);
}

// ---------------------------------------------------------------------------
// Transpose + fp32->bf16: in [K,N] row-major -> out [N,K] row-major (K-contig)
// ---------------------------------------------------------------------------
__global__ __launch_bounds__(256)
void transpose_bf16_k(const float* __restrict__ in, unsigned short* __restrict__ out,
                      int K, int N)
{
  __shared__ float t[32][33];
  const int n0 = blockIdx.x * 32, k0 = blockIdx.y * 32;
  const int tx = threadIdx.x & 31, ty = threadIdx.x >> 5;   // 32 x 8
  #pragma unroll
  for(int i=0;i<32;i+=8) t[ty+i][tx] = in[(long)(k0+ty+i)*N + n0 + tx];
  __syncthreads();
  #pragma unroll
  for(int i=0;i<32;i+=8) out[(long)(n0+ty+i)*K + k0 + tx] = f2bf(t[tx][ty+i]);
}

// ---------------------------------------------------------------------------
// V head-transpose: vbuf [NTOK, 1024] bf16 -> vt [b][h][64][2048] bf16
// ---------------------------------------------------------------------------
__global__ __launch_bounds__(256)
void transpose_v_head(const unsigned short* __restrict__ in,
                      unsigned short* __restrict__ out)
{
  __shared__ unsigned short t[64][72];
  const int s0 = blockIdx.x * 64, h = blockIdx.y, n = blockIdx.z;
  const int tid = threadIdx.x;
  #pragma unroll
  for(int i=0;i<2;i++){
    int id = i*256 + tid;
    int r = id >> 3, p = (id & 7) * 8;
    *(int4v*)&t[r][p] = *(const int4v*)&in[((long)(n*SEQ + s0 + r))*D_MODEL + h*HEAD_DIM + p];
  }
  __syncthreads();
  #pragma unroll
  for(int i=0;i<2;i++){
    int id = i*256 + tid;
    int d = id >> 3, p = (id & 7) * 8;
    ushort4v a, b;
    #pragma unroll
    for(int j=0;j<4;j++){ a[j] = t[p+j][d]; b[j] = t[p+4+j][d]; }
    unsigned short* dst = out + ((long)((n*NHEAD + h)*HEAD_DIM + d))*SEQ + s0 + p;
    *(ushort4v*)dst = a;
    *(ushort4v*)(dst+4) = b;
  }
}

// ---------------------------------------------------------------------------
// LayerNorm over 1024 cols, fp32 in -> bf16 out. One 256-thread block per row.
// ---------------------------------------------------------------------------
__global__ __launch_bounds__(256)
void ln_bf16(const float* __restrict__ x, const float* __restrict__ g,
             const float* __restrict__ b, unsigned short* __restrict__ out)
{
  const int row = blockIdx.x, tid = threadIdx.x;
  const float* xr = x + (long)row * D_MODEL;
  float4v v = *(const float4v*)(xr + tid*4);
  float s = v[0]+v[1]+v[2]+v[3];
  float q = v[0]*v[0]+v[1]*v[1]+v[2]*v[2]+v[3]*v[3];
  #pragma unroll
  for(int off=32; off; off>>=1){ s += __shfl_down(s, off); q += __shfl_down(q, off); }
  __shared__ float sb[4], qb[4], stat[2];
  const int w = tid>>6, lane = tid&63;
  if(lane==0){ sb[w]=s; qb[w]=q; }
  __syncthreads();
  if(tid==0){
    float S = sb[0]+sb[1]+sb[2]+sb[3];
    float Q = qb[0]+qb[1]+qb[2]+qb[3];
    float mean = S * (1.0f/D_MODEL);
    float var  = Q * (1.0f/D_MODEL) - mean*mean;
    stat[0] = mean;
    stat[1] = rsqrtf(var + 1e-5f);
  }
  __syncthreads();
  const float mean = stat[0], rstd = stat[1];
  ushort4v o;
  #pragma unroll
  for(int i=0;i<4;i++){
    int c = tid*4 + i;
    o[i] = f2bf((v[i]-mean)*rstd*g[c] + b[c]);
  }
  *(ushort4v*)(out + (long)row*D_MODEL + tid*4) = o;
}

// ---------------------------------------------------------------------------
// bf16 MFMA GEMM (same as round 1): C[M,N] = A[M,K] @ B[K,N]
// ---------------------------------------------------------------------------
template<int EPI>
__global__ __launch_bounds__(256, 2)
void gemm_bf16(const unsigned short* __restrict__ A,
               const unsigned short* __restrict__ Bt,
               const float* __restrict__ bias,
               const float* __restrict__ res,
               void* __restrict__ Cout,
               int M, int N, int K)
{
  __shared__ unsigned short As[128][40];
  __shared__ unsigned short Bs[128][40];
  const int tid = threadIdx.x;
  const int bm = blockIdx.x, bn = blockIdx.y;
  const int lane = tid & 63, wave = tid >> 6;
  const int wm = (wave >> 1) * 64, wn = (wave & 1) * 64;
  const int lrow = lane & 15, lquad = lane >> 4;

  float4v acc[4][4];
  #pragma unroll
  for(int i=0;i<4;i++)
    #pragma unroll
    for(int j=0;j<4;j++){ float4v z = {0.f,0.f,0.f,0.f}; acc[i][j] = z; }

  const long ra0 = (long)bm * 128;
  const long rb0 = (long)bn * 128;

  for(int k0 = 0; k0 < K; k0 += 32){
    __syncthreads();
    #pragma unroll
    for(int c=0;c<2;c++){
      int ch = c*256 + tid;
      int r = ch >> 2, pos = (ch & 3) * 8;
      *(int4v*)&As[r][pos] = *(const int4v*)(A  + (ra0 + r)*K + k0 + pos);
      *(int4v*)&Bs[r][pos] = *(const int4v*)(Bt + (rb0 + r)*K + k0 + pos);
    }
    __syncthreads();
    bf16x8 af[4], bfr[4];
    #pragma unroll
    for(int i=0;i<4;i++){
      af[i]  = *(const bf16x8*)&As[wm + i*16 + lrow][lquad*8];
      bfr[i] = *(const bf16x8*)&Bs[wn + i*16 + lrow][lquad*8];
    }
    #pragma unroll
    for(int i=0;i<4;i++)
      #pragma unroll
      for(int j=0;j<4;j++)
        acc[i][j] = __builtin_amdgcn_mfma_f32_16x16x32_bf16(af[i], bfr[j], acc[i][j], 0, 0, 0);
  }

  #pragma unroll
  for(int i=0;i<4;i++){
    #pragma unroll
    for(int r=0;r<4;r++){
      const int row = bm*128 + wm + i*16 + lquad*4 + r;
      const long base = (long)row * N + bn*128 + wn;
      #pragma unroll
      for(int j=0;j<4;j++){
        const int ct = j*16 + lrow;
        float val = acc[i][j][r] + bias[bn*128 + wn + ct];
        if constexpr (EPI == 1) val = fmaxf(val, 0.f);
        if constexpr (EPI == 2)
          ((float*)Cout)[base + ct] = val + res[base + ct];
        else
          ((unsigned short*)Cout)[base + ct] = f2bf(val);
      }
    }
  }
}

// ---------------------------------------------------------------------------
// MFMA flash attention. Block = 4 waves, each wave owns 32 q-rows (2 sets of
// 16). S^T = K @ Q^T per 128-row K-tile (C layout: q = lane&15 -> softmax
// reductions are shfl_xor 16/32). P^T repacked 4->8 granularity via per-wave
// LDS round trip. O^T = V^T @ P^T with V^T A-frags loaded straight from
// global vt[b][h][64][2048] (wave-level 16rows x 64B, L2-served).
// grid = (SEQ/128, NHEAD, NBATCH), block = 256.
// ---------------------------------------------------------------------------
__global__ __launch_bounds__(256, 2)
void attn_mfma(const unsigned short* __restrict__ qm,
               const unsigned short* __restrict__ km,
               const unsigned short* __restrict__ vt,
               unsigned short* __restrict__ om)
{
  __shared__ unsigned short Ks[128][72];      // 18432 B, pad 8
  __shared__ unsigned short Ps[4][32][136];   // 34816 B, per-wave scratch

  const int tid = threadIdx.x;
  const int w = tid >> 6, lane = tid & 63;
  const int l15 = lane & 15, quad = lane >> 4;
  const int h = blockIdx.y, n = blockIdx.z;
  const int qbase = blockIdx.x * 128 + w * 32;

  // Q B-frags: Q[q = l15][d = quad*8+j], two q-sets x two 32-d chunks
  bf16x8 qf[2][2];
  #pragma unroll
  for(int g=0; g<2; g++)
    #pragma unroll
    for(int ds=0; ds<2; ds++)
      qf[g][ds] = *(const bf16x8*)(qm + ((long)(n*SEQ + qbase + g*16 + l15))*D_MODEL
                                      + h*HEAD_DIM + ds*32 + quad*8);

  const unsigned short* vhead = vt + ((long)((n*NHEAD + h)*HEAD_DIM))*SEQ;

  float m[2]  = {-3.0e38f, -3.0e38f};
  float l[2]  = {0.f, 0.f};
  float4v oacc[4][2];
  #pragma unroll
  for(int dt=0; dt<4; dt++)
    #pragma unroll
    for(int g=0; g<2; g++){ float4v z={0.f,0.f,0.f,0.f}; oacc[dt][g]=z; }

  for(int s0 = 0; s0 < SEQ; s0 += 128){
    __syncthreads();   // previous tile's Ks reads done
    // ---- stage K tile 128x64 into LDS (4 x 16B chunks per thread) ----
    #pragma unroll
    for(int i=0;i<4;i++){
      int id = i*256 + tid;
      int r = id >> 3, p = (id & 7) * 8;
      *(int4v*)&Ks[r][p] = *(const int4v*)(km + ((long)(n*SEQ + s0 + r))*D_MODEL
                                              + h*HEAD_DIM + p);
    }
    // ---- issue all V^T A-frag loads for this tile (consumed in PV) ----
    bf16x8 vf[4][4];   // [kc][dt]
    #pragma unroll
    for(int kc=0; kc<4; kc++)
      #pragma unroll
      for(int dt=0; dt<4; dt++)
        vf[kc][dt] = *(const bf16x8*)(vhead + ((long)(dt*16 + l15))*SEQ
                                            + s0 + kc*32 + quad*8);
    __syncthreads();   // Ks ready

    // ---- S^T = K @ Q^T : 8 tiles of 16s x 16q per q-set ----
    float4v sacc[2][8];
    #pragma unroll
    for(int g=0;g<2;g++)
      #pragma unroll
      for(int c=0;c<8;c++){ float4v z={0.f,0.f,0.f,0.f}; sacc[g][c]=z; }
    #pragma unroll
    for(int c=0;c<8;c++){
      bf16x8 ka0 = *(const bf16x8*)&Ks[c*16 + l15][quad*8];
      bf16x8 ka1 = *(const bf16x8*)&Ks[c*16 + l15][32 + quad*8];
      sacc[0][c] = __builtin_amdgcn_mfma_f32_16x16x32_bf16(ka0, qf[0][0], sacc[0][c], 0,0,0);
      sacc[0][c] = __builtin_amdgcn_mfma_f32_16x16x32_bf16(ka1, qf[0][1], sacc[0][c], 0,0,0);
      sacc[1][c] = __builtin_amdgcn_mfma_f32_16x16x32_bf16(ka0, qf[1][0], sacc[1][c], 0,0,0);
      sacc[1][c] = __builtin_amdgcn_mfma_f32_16x16x32_bf16(ka1, qf[1][1], sacc[1][c], 0,0,0);
    }

    // ---- online softmax per q-set; P^T -> LDS (b64 packed) ----
    #pragma unroll
    for(int g=0; g<2; g++){
      float tm = -3.0e38f;
      #pragma unroll
      for(int c=0;c<8;c++)
        #pragma unroll
        for(int r=0;r<4;r++) tm = fmaxf(tm, sacc[g][c][r]);
      tm = fmaxf(tm, __shfl_xor(tm, 16));
      tm = fmaxf(tm, __shfl_xor(tm, 32));
      float mnew = fmaxf(m[g], tm);
      float alpha = exp2f((m[g] - mnew) * SCL);
      float ps = 0.f;
      #pragma unroll
      for(int c=0;c<8;c++){
        #pragma unroll
        for(int r=0;r<4;r++){
          float p = exp2f((sacc[g][c][r] - mnew) * SCL);
          sacc[g][c][r] = p;
          ps += p;
        }
      }
      ps += __shfl_xor(ps, 16);
      ps += __shfl_xor(ps, 32);
      l[g] = l[g]*alpha + ps;
      m[g] = mnew;
      #pragma unroll
      for(int dt=0; dt<4; dt++)
        #pragma unroll
        for(int r=0;r<4;r++) oacc[dt][g][r] *= alpha;
      // pack 4 consecutive-s P values -> b64 write at Ps[w][g*16+q][c*16+quad*4]
      #pragma unroll
      for(int c=0;c<8;c++){
        unsigned int d0 = pk2bf(sacc[g][c][0], sacc[g][c][1]);
        unsigned int d1 = pk2bf(sacc[g][c][2], sacc[g][c][3]);
        unsigned int* dst = (unsigned int*)&Ps[w][g*16 + l15][c*16 + quad*4];
        dst[0] = d0; dst[1] = d1;
      }
    }

    // ---- PV: O^T += V^T @ P^T ----
    #pragma unroll
    for(int kc=0; kc<4; kc++){
      bf16x8 pf0 = *(const bf16x8*)&Ps[w][     l15][kc*32 + quad*8];
      bf16x8 pf1 = *(const bf16x8*)&Ps[w][16 + l15][kc*32 + quad*8];
      #pragma unroll
      for(int dt=0; dt<4; dt++){
        oacc[dt][0] = __builtin_amdgcn_mfma_f32_16x16x32_bf16(vf[kc][dt], pf0, oacc[dt][0], 0,0,0);
        oacc[dt][1] = __builtin_amdgcn_mfma_f32_16x16x32_bf16(vf[kc][dt], pf1, oacc[dt][1], 0,0,0);
      }
    }
  }

  // ---- epilogue: normalize, transpose O^T -> O via per-wave LDS, store ----
  float inv[2] = {1.f/l[0], 1.f/l[1]};
  unsigned short* Os = &Ps[w][0][0];   // reuse, stride 80 (16B-aligned rows)
  #pragma unroll
  for(int g=0; g<2; g++){
    #pragma unroll
    for(int dt=0; dt<4; dt++){
      unsigned int d0 = pk2bf(oacc[dt][g][0]*inv[g], oacc[dt][g][1]*inv[g]);
      unsigned int d1 = pk2bf(oacc[dt][g][2]*inv[g], oacc[dt][g][3]*inv[g]);
      unsigned int* dst = (unsigned int*)&Os[(g*16 + l15)*80 + dt*16 + quad*4];
      dst[0] = d0; dst[1] = d1;
    }
  }
  // lane -> (q = lane>>1, half = lane&1): 4 x b128 reads, coalesced stores
  const int q = lane >> 1, half = lane & 1;
  unsigned short* orow = om + ((long)(n*SEQ + qbase + q))*D_MODEL + h*HEAD_DIM + half*32;
  #pragma unroll
  for(int j=0;j<4;j++){
    int4v vI = *(int4v*)&Os[q*80 + half*32 + j*8];
    *(int4v*)(orow + j*8) = vI;
  }
}

// ---------------------------------------------------------------------------
// Classifier head + GAN loss.
// ---------------------------------------------------------------------------
__global__ __launch_bounds__(256)
void loss_k(const float* __restrict__ xo, const float* __restrict__ wlr,
            const float* __restrict__ blr, float* __restrict__ out)
{
  const int tid = threadIdx.x, w = tid>>6, lane = tid&63;
  const float* row = xo + (long)w * SEQ * D_MODEL;
  float s = 0.f;
  for(int c=lane; c<D_MODEL; c+=64) s += row[c]*wlr[c];
  #pragma unroll
  for(int off=32; off; off>>=1) s += __shfl_down(s, off);
  __shared__ float lg[4];
  if(lane==0) lg[w] = s + blr[0];
  __syncthreads();
  if(tid==0){
    auto sp = [](float t){ return fmaxf(t, 0.f) + log1pf(__expf(-fabsf(t))); };
    float loss_real = 0.5f*(sp(-lg[0]) + sp(-lg[1]));
    float loss_fake = 0.5f*(sp( lg[2]) + sp( lg[3]));
    out[0] = 0.5f*(loss_fake + loss_real);
    out[1] = loss_fake;
  }
}

// ---------------------------------------------------------------------------
extern "C" void kernel_launch(void* const* d_in, const int* in_sizes, int n_in,
                              void* d_out, int out_size, void* d_ws, size_t ws_size,
                              hipStream_t stream)
{
  const float* x    = (const float*)d_in[0];
  const float* wq   = (const float*)d_in[1];
  const float* bq   = (const float*)d_in[2];
  const float* wk   = (const float*)d_in[3];
  const float* bk   = (const float*)d_in[4];
  const float* wv   = (const float*)d_in[5];
  const float* bv   = (const float*)d_in[6];
  const float* wo   = (const float*)d_in[7];
  const float* bo   = (const float*)d_in[8];
  const float* ln1g = (const float*)d_in[9];
  const float* ln1b = (const float*)d_in[10];
  const float* ln2g = (const float*)d_in[11];
  const float* ln2b = (const float*)d_in[12];
  const float* w1   = (const float*)d_in[13];
  const float* b1   = (const float*)d_in[14];
  const float* w2   = (const float*)d_in[15];
  const float* b2   = (const float*)d_in[16];
  const float* wlr  = (const float*)d_in[17];
  const float* blr  = (const float*)d_in[18];
  float* xout = (float*)d_out;

  // workspace layout (<=136 MB):
  char* ws = (char*)d_ws;
  unsigned short* xn   = (unsigned short*)(ws + (size_t)( 0<<20)); // 16MB (xn / xn2)
  unsigned short* wq_t = (unsigned short*)(ws + (size_t)(16<<20));
  unsigned short* wk_t = (unsigned short*)(ws + (size_t)(18<<20));
  unsigned short* wv_t = (unsigned short*)(ws + (size_t)(20<<20));
  unsigned short* wo_t = (unsigned short*)(ws + (size_t)(22<<20));
  unsigned short* w1_t = (unsigned short*)(ws + (size_t)(24<<20)); // 8MB
  unsigned short* w2_t = (unsigned short*)(ws + (size_t)(32<<20)); // 8MB
  unsigned short* qb   = (unsigned short*)(ws + (size_t)(40<<20)); // 16MB
  unsigned short* kbuf = (unsigned short*)(ws + (size_t)(56<<20)); // 16MB
  unsigned short* vbuf = (unsigned short*)(ws + (size_t)(72<<20)); // 16MB
  unsigned short* attn = (unsigned short*)(ws + (size_t)(88<<20)); // 16MB
  float*          x1   = (float*)         (ws + (size_t)(104<<20));// 32MB fp32
  unsigned short* vt   = (unsigned short*)(ws + (size_t)(104<<20));// 16MB, dead before x1 written
  unsigned short* hid  = (unsigned short*)(ws + (size_t)(40<<20)); // 64MB, aliases q/k/v/attn

  dim3 blk(256);

  transpose_bf16_k<<<dim3(32,32),  blk, 0, stream>>>(wq, wq_t, 1024, 1024);
  transpose_bf16_k<<<dim3(32,32),  blk, 0, stream>>>(wk, wk_t, 1024, 1024);
  transpose_bf16_k<<<dim3(32,32),  blk, 0, stream>>>(wv, wv_t, 1024, 1024);
  transpose_bf16_k<<<dim3(32,32),  blk, 0, stream>>>(wo, wo_t, 1024, 1024);
  transpose_bf16_k<<<dim3(128,32), blk, 0, stream>>>(w1, w1_t, 1024, 4096);
  transpose_bf16_k<<<dim3(32,128), blk, 0, stream>>>(w2, w2_t, 4096, 1024);

  ln_bf16<<<NTOK, blk, 0, stream>>>(x, ln1g, ln1b, xn);

  gemm_bf16<0><<<dim3(64,8),  blk, 0, stream>>>(xn, wq_t, bq, nullptr, qb,   NTOK, 1024, 1024);
  gemm_bf16<0><<<dim3(64,8),  blk, 0, stream>>>(xn, wk_t, bk, nullptr, kbuf, NTOK, 1024, 1024);
  gemm_bf16<0><<<dim3(64,8),  blk, 0, stream>>>(xn, wv_t, bv, nullptr, vbuf, NTOK, 1024, 1024);

  transpose_v_head<<<dim3(SEQ/64, NHEAD, NBATCH), blk, 0, stream>>>(vbuf, vt);

  attn_mfma<<<dim3(SEQ/128, NHEAD, NBATCH), blk, 0, stream>>>(qb, kbuf, vt, attn);

  gemm_bf16<2><<<dim3(64,8),  blk, 0, stream>>>(attn, wo_t, bo, x, x1, NTOK, 1024, 1024);

  ln_bf16<<<NTOK, blk, 0, stream>>>(x1, ln2g, ln2b, xn);

  gemm_bf16<1><<<dim3(64,32), blk, 0, stream>>>(xn,  w1_t, b1, nullptr, hid, NTOK, D_FF, 1024);
  gemm_bf16<2><<<dim3(64,8),  blk, 0, stream>>>(hid, w2_t, b2, x1, xout,     NTOK, 1024, D_FF);

  loss_k<<<1, blk, 0, stream>>>(xout, wlr, blr, xout + (size_t)NTOK*D_MODEL);
}

// Round 3
// 563.734 us; speedup vs baseline: 3.3041x; 1.1961x over previous
//
#include <hip/hip_runtime.h>

typedef float  float4v  __attribute__((ext_vector_type(4)));
typedef int    int4v    __attribute__((ext_vector_type(4)));
typedef unsigned short ushort4v __attribute__((ext_vector_type(4)));
typedef __bf16 bf16x8   __attribute__((ext_vector_type(8)));
typedef __bf16 bf16x2   __attribute__((ext_vector_type(2)));

#define D_MODEL 1024
#define NHEAD   16
#define HEAD_DIM 64
#define D_FF    4096
#define SEQ     2048
#define NBATCH  4
#define NTOK    (SEQ*NBATCH)   // 8192
#define QSTR    3072           // fused qkv row stride

// softmax scale folded into exp2: 1/sqrt(64) * log2(e)
#define SCL 0.18033688011112042f

__device__ __forceinline__ unsigned short f2bf(float f){
  __bf16 h = (__bf16)f;                       // native cvt on gfx950
  return __builtin_bit_cast(unsigned short, h);
}
__device__ __forceinline__ float bf2f(unsigned short h){
  unsigned int u = ((unsigned int)h) << 16;
  return __builtin_bit_cast(float, u);
}
__device__ __forceinline__ unsigned int pk2bf(float lo, float hi){
  bf16x2 v; v[0] = (__bf16)lo; v[1] = (__bf16)hi;
  return __builtin_bit_cast(unsigned int, v);
}

// async global->LDS, 16B per lane; lds dst = wave-uniform base + lane*16
typedef const __attribute__((address_space(1))) void* as1cv;
typedef __attribute__((address_space(3))) void* as3v;
__device__ __forceinline__ void gl_lds16(const void* g, void* l){
  __builtin_amdgcn_global_load_lds((as1cv)(unsigned long long)g,
                                   (as3v)(unsigned int)(unsigned long long)l,
                                   16, 0, 0);
}

// ---------------------------------------------------------------------------
// Transpose + fp32->bf16: in [K,N] row-major -> out [N,K] row-major (K-contig)
// ---------------------------------------------------------------------------
__global__ __launch_bounds__(256)
void transpose_bf16_k(const float* __restrict__ in, unsigned short* __restrict__ out,
                      int K, int N)
{
  __shared__ float t[32][33];
  const int n0 = blockIdx.x * 32, k0 = blockIdx.y * 32;
  const int tx = threadIdx.x & 31, ty = threadIdx.x >> 5;   // 32 x 8
  #pragma unroll
  for(int i=0;i<32;i+=8) t[ty+i][tx] = in[(long)(k0+ty+i)*N + n0 + tx];
  __syncthreads();
  #pragma unroll
  for(int i=0;i<32;i+=8) out[(long)(n0+ty+i)*K + k0 + tx] = f2bf(t[tx][ty+i]);
}

// concat q/k/v biases -> [3072]
__global__ __launch_bounds__(256)
void concat_bias(const float* __restrict__ bq, const float* __restrict__ bk,
                 const float* __restrict__ bv, float* __restrict__ out)
{
  int i = blockIdx.x*256 + threadIdx.x;
  float v = (i < 1024) ? bq[i] : (i < 2048) ? bk[i-1024] : bv[i-2048];
  out[i] = v;
}

// ---------------------------------------------------------------------------
// V head-transpose: qkv v-part [NTOK, 3072] bf16 -> vt [b][h][64][2048] bf16
// ---------------------------------------------------------------------------
__global__ __launch_bounds__(256)
void transpose_v_head(const unsigned short* __restrict__ in,
                      unsigned short* __restrict__ out)
{
  __shared__ unsigned short t[64][72];
  const int s0 = blockIdx.x * 64, h = blockIdx.y, n = blockIdx.z;
  const int tid = threadIdx.x;
  #pragma unroll
  for(int i=0;i<2;i++){
    int id = i*256 + tid;
    int r = id >> 3, p = (id & 7) * 8;
    *(int4v*)&t[r][p] = *(const int4v*)&in[((long)(n*SEQ + s0 + r))*QSTR + h*HEAD_DIM + p];
  }
  __syncthreads();
  #pragma unroll
  for(int i=0;i<2;i++){
    int id = i*256 + tid;
    int d = id >> 3, p = (id & 7) * 8;
    ushort4v a, b;
    #pragma unroll
    for(int j=0;j<4;j++){ a[j] = t[p+j][d]; b[j] = t[p+4+j][d]; }
    unsigned short* dst = out + ((long)((n*NHEAD + h)*HEAD_DIM + d))*SEQ + s0 + p;
    *(ushort4v*)dst = a;
    *(ushort4v*)(dst+4) = b;
  }
}

// ---------------------------------------------------------------------------
// LayerNorm over 1024 cols, fp32 in -> bf16 out. One 256-thread block per row.
// ---------------------------------------------------------------------------
__global__ __launch_bounds__(256)
void ln_bf16(const float* __restrict__ x, const float* __restrict__ g,
             const float* __restrict__ b, unsigned short* __restrict__ out)
{
  const int row = blockIdx.x, tid = threadIdx.x;
  const float* xr = x + (long)row * D_MODEL;
  float4v v = *(const float4v*)(xr + tid*4);
  float s = v[0]+v[1]+v[2]+v[3];
  float q = v[0]*v[0]+v[1]*v[1]+v[2]*v[2]+v[3]*v[3];
  #pragma unroll
  for(int off=32; off; off>>=1){ s += __shfl_down(s, off); q += __shfl_down(q, off); }
  __shared__ float sb[4], qb[4], stat[2];
  const int w = tid>>6, lane = tid&63;
  if(lane==0){ sb[w]=s; qb[w]=q; }
  __syncthreads();
  if(tid==0){
    float S = sb[0]+sb[1]+sb[2]+sb[3];
    float Q = qb[0]+qb[1]+qb[2]+qb[3];
    float mean = S * (1.0f/D_MODEL);
    float var  = Q * (1.0f/D_MODEL) - mean*mean;
    stat[0] = mean;
    stat[1] = rsqrtf(var + 1e-5f);
  }
  __syncthreads();
  const float mean = stat[0], rstd = stat[1];
  ushort4v o;
  #pragma unroll
  for(int i=0;i<4;i++){
    int c = tid*4 + i;
    o[i] = f2bf((v[i]-mean)*rstd*g[c] + b[c]);
  }
  *(ushort4v*)(out + (long)row*D_MODEL + tid*4) = o;
}

// ---------------------------------------------------------------------------
// m97-style bf16 MFMA GEMM: C[M,N] = A[M,K] @ B[K,N], BK=64,
// global_load_lds width-16 staging, XOR-swizzled LDS (conflict-free b128).
// LDS[row][c] (c = 16B chunk 0..7) holds global chunk c ^ (row&7).
// A: [M,K] bf16, Bt: [N,K] bf16. 128x128 tile, 4 waves 2x2, 64x64/wave.
// EPI: 0 bias->bf16; 1 bias+relu->bf16; 2 bias+res(f32)->f32.
// ---------------------------------------------------------------------------
template<int EPI>
__global__ __launch_bounds__(256, 2)
void gemm_bf16(const unsigned short* __restrict__ A,
               const unsigned short* __restrict__ Bt,
               const float* __restrict__ bias,
               const float* __restrict__ res,
               void* __restrict__ Cout,
               int M, int N, int K)
{
  __shared__ unsigned short As[128][64];   // 16 KB, no pad (swizzled)
  __shared__ unsigned short Bs[128][64];
  const int tid = threadIdx.x;
  const int bm = blockIdx.x, bn = blockIdx.y;
  const int lane = tid & 63, w = tid >> 6;
  const int wm = (w >> 1) * 64, wn = (w & 1) * 64;
  const int l15 = lane & 15, quad = lane >> 4;
  const int r8 = lane >> 3, c8 = lane & 7;
  const int swc = c8 ^ r8;                 // swizzled chunk this lane fetches

  float4v acc[4][4];
  #pragma unroll
  for(int i=0;i<4;i++)
    #pragma unroll
    for(int j=0;j<4;j++){ float4v z = {0.f,0.f,0.f,0.f}; acc[i][j] = z; }

  const unsigned short* Abase = A  + ((long)bm*128 + w*32 + r8)*K + swc*8;
  const unsigned short* Bbase = Bt + ((long)bn*128 + w*32 + r8)*K + swc*8;
  unsigned short* AsW = &As[w*32][0];
  unsigned short* BsW = &Bs[w*32][0];

  for(int k0 = 0; k0 < K; k0 += 64){
    __syncthreads();                       // prev tile reads done
    #pragma unroll
    for(int i=0;i<4;i++){
      gl_lds16(Abase + (long)i*8*K + k0, AsW + i*8*64);
      gl_lds16(Bbase + (long)i*8*K + k0, BsW + i*8*64);
    }
    __syncthreads();                       // staging visible (vmcnt drain)

    #pragma unroll
    for(int kh=0; kh<2; kh++){
      const int jsw = ((kh*4 + quad) ^ (l15 & 7)) * 8;
      bf16x8 af[4], bfr[4];
      #pragma unroll
      for(int i=0;i<4;i++){
        af[i]  = *(const bf16x8*)&As[wm + i*16 + l15][jsw];
        bfr[i] = *(const bf16x8*)&Bs[wn + i*16 + l15][jsw];
      }
      #pragma unroll
      for(int i=0;i<4;i++)
        #pragma unroll
        for(int j=0;j<4;j++)
          acc[i][j] = __builtin_amdgcn_mfma_f32_16x16x32_bf16(af[i], bfr[j], acc[i][j], 0, 0, 0);
    }
  }

  #pragma unroll
  for(int i=0;i<4;i++){
    #pragma unroll
    for(int r=0;r<4;r++){
      const int row = bm*128 + wm + i*16 + quad*4 + r;
      const long base = (long)row * N + bn*128 + wn;
      #pragma unroll
      for(int j=0;j<4;j++){
        const int ct = j*16 + l15;
        float val = acc[i][j][r] + bias[bn*128 + wn + ct];
        if constexpr (EPI == 1) val = fmaxf(val, 0.f);
        if constexpr (EPI == 2)
          ((float*)Cout)[base + ct] = val + res[base + ct];
        else
          ((unsigned short*)Cout)[base + ct] = f2bf(val);
      }
    }
  }
}

// ---------------------------------------------------------------------------
// MFMA flash attention (unchanged structure from R2, qkv fused stride).
// grid = (SEQ/128, NHEAD, NBATCH), block = 256.
// ---------------------------------------------------------------------------
__global__ __launch_bounds__(256, 2)
void attn_mfma(const unsigned short* __restrict__ qm,
               const unsigned short* __restrict__ km,
               const unsigned short* __restrict__ vt,
               unsigned short* __restrict__ om)
{
  __shared__ unsigned short Ks[128][72];      // 18432 B, pad 8
  __shared__ unsigned short Ps[4][32][136];   // 34816 B, per-wave scratch

  const int tid = threadIdx.x;
  const int w = tid >> 6, lane = tid & 63;
  const int l15 = lane & 15, quad = lane >> 4;
  const int h = blockIdx.y, n = blockIdx.z;
  const int qbase = blockIdx.x * 128 + w * 32;

  bf16x8 qf[2][2];
  #pragma unroll
  for(int g=0; g<2; g++)
    #pragma unroll
    for(int ds=0; ds<2; ds++)
      qf[g][ds] = *(const bf16x8*)(qm + ((long)(n*SEQ + qbase + g*16 + l15))*QSTR
                                      + h*HEAD_DIM + ds*32 + quad*8);

  const unsigned short* vhead = vt + ((long)((n*NHEAD + h)*HEAD_DIM))*SEQ;

  float m[2]  = {-3.0e38f, -3.0e38f};
  float l[2]  = {0.f, 0.f};
  float4v oacc[4][2];
  #pragma unroll
  for(int dt=0; dt<4; dt++)
    #pragma unroll
    for(int g=0; g<2; g++){ float4v z={0.f,0.f,0.f,0.f}; oacc[dt][g]=z; }

  for(int s0 = 0; s0 < SEQ; s0 += 128){
    __syncthreads();
    #pragma unroll
    for(int i=0;i<4;i++){
      int id = i*256 + tid;
      int r = id >> 3, p = (id & 7) * 8;
      *(int4v*)&Ks[r][p] = *(const int4v*)(km + ((long)(n*SEQ + s0 + r))*QSTR
                                              + h*HEAD_DIM + p);
    }
    bf16x8 vf[4][4];   // [kc][dt]
    #pragma unroll
    for(int kc=0; kc<4; kc++)
      #pragma unroll
      for(int dt=0; dt<4; dt++)
        vf[kc][dt] = *(const bf16x8*)(vhead + ((long)(dt*16 + l15))*SEQ
                                            + s0 + kc*32 + quad*8);
    __syncthreads();

    float4v sacc[2][8];
    #pragma unroll
    for(int g=0;g<2;g++)
      #pragma unroll
      for(int c=0;c<8;c++){ float4v z={0.f,0.f,0.f,0.f}; sacc[g][c]=z; }
    #pragma unroll
    for(int c=0;c<8;c++){
      bf16x8 ka0 = *(const bf16x8*)&Ks[c*16 + l15][quad*8];
      bf16x8 ka1 = *(const bf16x8*)&Ks[c*16 + l15][32 + quad*8];
      sacc[0][c] = __builtin_amdgcn_mfma_f32_16x16x32_bf16(ka0, qf[0][0], sacc[0][c], 0,0,0);
      sacc[0][c] = __builtin_amdgcn_mfma_f32_16x16x32_bf16(ka1, qf[0][1], sacc[0][c], 0,0,0);
      sacc[1][c] = __builtin_amdgcn_mfma_f32_16x16x32_bf16(ka0, qf[1][0], sacc[1][c], 0,0,0);
      sacc[1][c] = __builtin_amdgcn_mfma_f32_16x16x32_bf16(ka1, qf[1][1], sacc[1][c], 0,0,0);
    }

    #pragma unroll
    for(int g=0; g<2; g++){
      float tm = -3.0e38f;
      #pragma unroll
      for(int c=0;c<8;c++)
        #pragma unroll
        for(int r=0;r<4;r++) tm = fmaxf(tm, sacc[g][c][r]);
      tm = fmaxf(tm, __shfl_xor(tm, 16));
      tm = fmaxf(tm, __shfl_xor(tm, 32));
      float mnew = fmaxf(m[g], tm);
      float alpha = exp2f((m[g] - mnew) * SCL);
      float ps = 0.f;
      #pragma unroll
      for(int c=0;c<8;c++){
        #pragma unroll
        for(int r=0;r<4;r++){
          float p = exp2f((sacc[g][c][r] - mnew) * SCL);
          sacc[g][c][r] = p;
          ps += p;
        }
      }
      ps += __shfl_xor(ps, 16);
      ps += __shfl_xor(ps, 32);
      l[g] = l[g]*alpha + ps;
      m[g] = mnew;
      #pragma unroll
      for(int dt=0; dt<4; dt++)
        #pragma unroll
        for(int r=0;r<4;r++) oacc[dt][g][r] *= alpha;
      #pragma unroll
      for(int c=0;c<8;c++){
        unsigned int d0 = pk2bf(sacc[g][c][0], sacc[g][c][1]);
        unsigned int d1 = pk2bf(sacc[g][c][2], sacc[g][c][3]);
        unsigned int* dst = (unsigned int*)&Ps[w][g*16 + l15][c*16 + quad*4];
        dst[0] = d0; dst[1] = d1;
      }
    }

    #pragma unroll
    for(int kc=0; kc<4; kc++){
      bf16x8 pf0 = *(const bf16x8*)&Ps[w][     l15][kc*32 + quad*8];
      bf16x8 pf1 = *(const bf16x8*)&Ps[w][16 + l15][kc*32 + quad*8];
      #pragma unroll
      for(int dt=0; dt<4; dt++){
        oacc[dt][0] = __builtin_amdgcn_mfma_f32_16x16x32_bf16(vf[kc][dt], pf0, oacc[dt][0], 0,0,0);
        oacc[dt][1] = __builtin_amdgcn_mfma_f32_16x16x32_bf16(vf[kc][dt], pf1, oacc[dt][1], 0,0,0);
      }
    }
  }

  float inv[2] = {1.f/l[0], 1.f/l[1]};
  unsigned short* Os = &Ps[w][0][0];   // reuse, stride 80
  #pragma unroll
  for(int g=0; g<2; g++){
    #pragma unroll
    for(int dt=0; dt<4; dt++){
      unsigned int d0 = pk2bf(oacc[dt][g][0]*inv[g], oacc[dt][g][1]*inv[g]);
      unsigned int d1 = pk2bf(oacc[dt][g][2]*inv[g], oacc[dt][g][3]*inv[g]);
      unsigned int* dst = (unsigned int*)&Os[(g*16 + l15)*80 + dt*16 + quad*4];
      dst[0] = d0; dst[1] = d1;
    }
  }
  const int q = lane >> 1, half = lane & 1;
  unsigned short* orow = om + ((long)(n*SEQ + qbase + q))*D_MODEL + h*HEAD_DIM + half*32;
  #pragma unroll
  for(int j=0;j<4;j++){
    int4v vI = *(int4v*)&Os[q*80 + half*32 + j*8];
    *(int4v*)(orow + j*8) = vI;
  }
}

// ---------------------------------------------------------------------------
// Classifier head + GAN loss.
// ---------------------------------------------------------------------------
__global__ __launch_bounds__(256)
void loss_k(const float* __restrict__ xo, const float* __restrict__ wlr,
            const float* __restrict__ blr, float* __restrict__ out)
{
  const int tid = threadIdx.x, w = tid>>6, lane = tid&63;
  const float* row = xo + (long)w * SEQ * D_MODEL;
  float s = 0.f;
  for(int c=lane; c<D_MODEL; c+=64) s += row[c]*wlr[c];
  #pragma unroll
  for(int off=32; off; off>>=1) s += __shfl_down(s, off);
  __shared__ float lg[4];
  if(lane==0) lg[w] = s + blr[0];
  __syncthreads();
  if(tid==0){
    auto sp = [](float t){ return fmaxf(t, 0.f) + log1pf(__expf(-fabsf(t))); };
    float loss_real = 0.5f*(sp(-lg[0]) + sp(-lg[1]));
    float loss_fake = 0.5f*(sp( lg[2]) + sp( lg[3]));
    out[0] = 0.5f*(loss_fake + loss_real);
    out[1] = loss_fake;
  }
}

// ---------------------------------------------------------------------------
extern "C" void kernel_launch(void* const* d_in, const int* in_sizes, int n_in,
                              void* d_out, int out_size, void* d_ws, size_t ws_size,
                              hipStream_t stream)
{
  const float* x    = (const float*)d_in[0];
  const float* wq   = (const float*)d_in[1];
  const float* bq   = (const float*)d_in[2];
  const float* wk   = (const float*)d_in[3];
  const float* bk   = (const float*)d_in[4];
  const float* wv   = (const float*)d_in[5];
  const float* bv   = (const float*)d_in[6];
  const float* wo   = (const float*)d_in[7];
  const float* bo   = (const float*)d_in[8];
  const float* ln1g = (const float*)d_in[9];
  const float* ln1b = (const float*)d_in[10];
  const float* ln2g = (const float*)d_in[11];
  const float* ln2b = (const float*)d_in[12];
  const float* w1   = (const float*)d_in[13];
  const float* b1   = (const float*)d_in[14];
  const float* w2   = (const float*)d_in[15];
  const float* b2   = (const float*)d_in[16];
  const float* wlr  = (const float*)d_in[17];
  const float* blr  = (const float*)d_in[18];
  float* xout = (float*)d_out;

  // workspace layout (<=121 MB):
  char* ws = (char*)d_ws;
  unsigned short* xn     = (unsigned short*)(ws + (size_t)(  0<<20)); // 16MB (xn / xn2)
  unsigned short* wqkv_t = (unsigned short*)(ws + (size_t)( 16<<20)); //  6MB [3072][1024]
  unsigned short* wo_t   = (unsigned short*)(ws + (size_t)( 22<<20)); //  2MB
  unsigned short* w1_t   = (unsigned short*)(ws + (size_t)( 24<<20)); //  8MB
  unsigned short* w2_t   = (unsigned short*)(ws + (size_t)( 32<<20)); //  8MB
  unsigned short* qkv    = (unsigned short*)(ws + (size_t)( 40<<20)); // 48MB [8192][3072]
  unsigned short* attn   = (unsigned short*)(ws + (size_t)( 88<<20)); // 16MB [8192][1024]
  unsigned short* vt     = (unsigned short*)(ws + (size_t)(104<<20)); // 16MB [b][h][64][2048]
  float*          bqkv   = (float*)         (ws + (size_t)(120<<20)); // 12KB
  unsigned short* hid    = (unsigned short*)(ws + (size_t)( 40<<20)); // 64MB, aliases qkv+attn

  dim3 blk(256);

  transpose_bf16_k<<<dim3(32,32),  blk, 0, stream>>>(wq, wqkv_t,               1024, 1024);
  transpose_bf16_k<<<dim3(32,32),  blk, 0, stream>>>(wk, wqkv_t + 1024*1024,   1024, 1024);
  transpose_bf16_k<<<dim3(32,32),  blk, 0, stream>>>(wv, wqkv_t + 2*1024*1024, 1024, 1024);
  transpose_bf16_k<<<dim3(32,32),  blk, 0, stream>>>(wo, wo_t, 1024, 1024);
  transpose_bf16_k<<<dim3(128,32), blk, 0, stream>>>(w1, w1_t, 1024, 4096);
  transpose_bf16_k<<<dim3(32,128), blk, 0, stream>>>(w2, w2_t, 4096, 1024);
  concat_bias<<<12, blk, 0, stream>>>(bq, bk, bv, bqkv);

  ln_bf16<<<NTOK, blk, 0, stream>>>(x, ln1g, ln1b, xn);

  // fused QKV projection: [8192,1024] @ [1024,3072]
  gemm_bf16<0><<<dim3(64,24), blk, 0, stream>>>(xn, wqkv_t, bqkv, nullptr, qkv, NTOK, QSTR, 1024);

  transpose_v_head<<<dim3(SEQ/64, NHEAD, NBATCH), blk, 0, stream>>>(qkv + 2048, vt);

  attn_mfma<<<dim3(SEQ/128, NHEAD, NBATCH), blk, 0, stream>>>(qkv, qkv + 1024, vt, attn);

  // out projection + residual -> xout (fp32)
  gemm_bf16<2><<<dim3(64,8),  blk, 0, stream>>>(attn, wo_t, bo, x, xout, NTOK, 1024, 1024);

  ln_bf16<<<NTOK, blk, 0, stream>>>(xout, ln2g, ln2b, xn);

  // FFN
  gemm_bf16<1><<<dim3(64,32), blk, 0, stream>>>(xn,  w1_t, b1, nullptr, hid, NTOK, D_FF, 1024);
  gemm_bf16<2><<<dim3(64,8),  blk, 0, stream>>>(hid, w2_t, b2, xout, xout,   NTOK, 1024, D_FF);

  loss_k<<<1, blk, 0, stream>>>(xout, wlr, blr, xout + (size_t)NTOK*D_MODEL);
}